// Round 2
// baseline (826.209 us; speedup 1.0000x reference)
//
#include <hip/hip_runtime.h>
#include <math.h>

#define GROUPS_PER_BLOCK 16
#define THREADS 256

// ---- 16-lane-group sum via DPP row rotates (VALU pipe, no LDS) ----
template<int CTRL>
__device__ __forceinline__ float dpp_add(float x) {
    int xi = __builtin_bit_cast(int, x);
    int yi = __builtin_amdgcn_update_dpp(0, xi, CTRL, 0xF, 0xF, false);
    return x + __builtin_bit_cast(float, yi);
}
__device__ __forceinline__ float group16_sum(float x) {
    x = dpp_add<0x121>(x);  // row_ror:1
    x = dpp_add<0x122>(x);  // row_ror:2
    x = dpp_add<0x124>(x);  // row_ror:4
    x = dpp_add<0x128>(x);  // row_ror:8
    return x;               // every lane holds the 16-lane sum
}

// ---- setup: W[7,12,8,16] -> Wt[(n*8+j)*4+kq][m] of float4 (lane-coalesced) ----
__global__ void transpose_W_kernel(const float* __restrict__ W,
                                   float4* __restrict__ Wt) {
    int i = blockIdx.x * blockDim.x + threadIdx.x;   // 7*8*4*12 = 2688 outputs
    if (i < 2688) {
        int m  = i % 12;
        int r  = i / 12;          // (n*8+j)*4+kq
        int kq = r & 3;
        int j  = (r >> 2) & 7;
        int n  = r >> 5;
        const float* src = W + (((size_t)(n * 12 + m) * 8 + j) * 16 + kq * 4);
        Wt[i] = *(const float4*)src;
    }
}

// One 16-lane group per batch element; lane t owns output capsule m=min(t,11).
__global__ __launch_bounds__(THREADS, 4) void capsnet_kernel(
    const float* __restrict__ x,      // [B,210]
    const float* __restrict__ W_pc,   // [7,8,30]
    const float* __restrict__ b_pc,   // [7,8]
    const float4* __restrict__ Wt,    // transposed W, see above
    const int*  __restrict__ p_niter,
    float* __restrict__ out,          // [B,12]
    int B)
{
    __shared__ float xs[GROUPS_PER_BLOCK][210];
    __shared__ float us[GROUPS_PER_BLOCK][56];

    const int tid = threadIdx.x;
    const int g   = tid >> 4;
    const int t   = tid & 15;
    int b = blockIdx.x * GROUPS_PER_BLOCK + g;
    const bool valid_b = (b < B);
    if (!valid_b) b = B - 1;
    const int niter = *p_niter;

    // ---- stage x[b] into LDS ----
    {
        const float2* xrow = (const float2*)(x + (size_t)b * 210);
        float2* xdst = (float2*)&xs[g][0];
        #pragma unroll
        for (int i = 0; i < 7; ++i) {
            int idx = t + 16 * i;
            if (idx < 105) xdst[idx] = xrow[idx];
        }
    }
    __syncthreads();

    // ---- primary capsules ----
    #pragma unroll
    for (int i = 0; i < 4; ++i) {
        int idx = t + 16 * i;                 // idx = n*8 + o (56 outputs)
        if (idx < 56) {
            int n = idx >> 3;
            const float2* wrow2 = (const float2*)(W_pc + idx * 30);
            const float2* xr2   = (const float2*)&xs[g][n * 30];
            float acc = b_pc[idx];
            #pragma unroll
            for (int gg = 0; gg < 15; ++gg) {
                float2 wv = wrow2[gg];
                float2 xv = xr2[gg];
                acc += xv.x * wv.x;
                acc += xv.y * wv.y;
            }
            us[g][idx] = acc;
        }
    }
    __syncthreads();

    // ---- squash primary capsules (lanes 0..6, one n each) ----
    if (t < 7) {
        float vals[8];
        float s2 = 0.f;
        #pragma unroll
        for (int o = 0; o < 8; ++o) {
            vals[o] = us[g][t * 8 + o];
            s2 += vals[o] * vals[o];
        }
        float nrm = sqrtf(s2);
        float f = nrm / ((1.f + s2) * (nrm + 1e-8f));
        #pragma unroll
        for (int o = 0; o < 8; ++o) us[g][t * 8 + o] = vals[o] * f;
    }
    __syncthreads();

    // ---- u_hat[n][m=t][k] from transposed W (coalesced float4 loads) ----
    const int m = (t < 12) ? t : 11;
    float uh[7][16];
    #pragma unroll
    for (int n = 0; n < 7; ++n) {
        float uu[8];
        {
            float4 a  = *(const float4*)&us[g][n * 8];
            float4 c4 = *(const float4*)&us[g][n * 8 + 4];
            uu[0] = a.x;  uu[1] = a.y;  uu[2] = a.z;  uu[3] = a.w;
            uu[4] = c4.x; uu[5] = c4.y; uu[6] = c4.z; uu[7] = c4.w;
        }
        #pragma unroll
        for (int k = 0; k < 16; ++k) uh[n][k] = 0.f;
        #pragma unroll
        for (int j = 0; j < 8; ++j) {
            float uj = uu[j];
            const float4* wb = Wt + ((n * 8 + j) * 4) * 12 + m;
            #pragma unroll
            for (int kq = 0; kq < 4; ++kq) {
                float4 w = wb[kq * 12];
                uh[n][kq * 4 + 0] += uj * w.x;
                uh[n][kq * 4 + 1] += uj * w.y;
                uh[n][kq * 4 + 2] += uj * w.z;
                uh[n][kq * 4 + 3] += uj * w.w;
            }
        }
    }

    // ---- dynamic routing ----
    const bool active = (t < 12);
    float blog[7];
    float vnorm = 0.f;

    // iteration 0: b == 0  =>  c == 1/12 exactly (softmax of zeros)
    {
        float s[16];
        #pragma unroll
        for (int k = 0; k < 16; ++k) s[k] = uh[0][k];
        #pragma unroll
        for (int n = 1; n < 7; ++n)
            #pragma unroll
            for (int k = 0; k < 16; ++k) s[k] += uh[n][k];
        const float c0 = 1.0f / 12.0f;
        #pragma unroll
        for (int k = 0; k < 16; ++k) s[k] *= c0;
        float s2 = 0.f;
        #pragma unroll
        for (int k = 0; k < 16; ++k) s2 += s[k] * s[k];
        float nrm = sqrtf(s2);
        float f = nrm / ((1.f + s2) * (nrm + 1e-8f));
        if (niter == 1) {
            vnorm = f * nrm;
        } else {
            #pragma unroll
            for (int k = 0; k < 16; ++k) s[k] *= f;   // s -> v
            #pragma unroll
            for (int n = 0; n < 7; ++n) {
                float d = 0.f;
                #pragma unroll
                for (int k = 0; k < 16; ++k) d += uh[n][k] * s[k];
                blog[n] = d;                           // b was 0
            }
        }
    }

    for (int it = 1; it < niter; ++it) {
        // softmax over m (logits bounded, no max-subtraction needed;
        // inactive lanes contribute exp=0)
        float c[7];
        #pragma unroll
        for (int n = 0; n < 7; ++n) {
            float e  = active ? __expf(blog[n]) : 0.f;
            float sm = group16_sum(e);
            c[n] = e / sm;
        }
        float s[16];
        #pragma unroll
        for (int k = 0; k < 16; ++k) s[k] = 0.f;
        #pragma unroll
        for (int n = 0; n < 7; ++n) {
            float cn = c[n];
            #pragma unroll
            for (int k = 0; k < 16; ++k) s[k] += cn * uh[n][k];
        }
        float s2 = 0.f;
        #pragma unroll
        for (int k = 0; k < 16; ++k) s2 += s[k] * s[k];
        float nrm = sqrtf(s2);
        float f = nrm / ((1.f + s2) * (nrm + 1e-8f));
        if (it == niter - 1) {
            vnorm = f * nrm;
        } else {
            #pragma unroll
            for (int k = 0; k < 16; ++k) s[k] *= f;   // s -> v
            #pragma unroll
            for (int n = 0; n < 7; ++n) {
                float d = 0.f;
                #pragma unroll
                for (int k = 0; k < 16; ++k) d += uh[n][k] * s[k];
                blog[n] += d;
            }
        }
    }

    if (active && valid_b) out[(size_t)b * 12 + t] = vnorm;
}

extern "C" void kernel_launch(void* const* d_in, const int* in_sizes, int n_in,
                              void* d_out, int out_size, void* d_ws, size_t ws_size,
                              hipStream_t stream) {
    const float* x    = (const float*)d_in[0];
    const float* W_pc = (const float*)d_in[1];
    const float* b_pc = (const float*)d_in[2];
    const float* W    = (const float*)d_in[3];
    const int* niter  = (const int*)d_in[4];
    float* out = (float*)d_out;

    float4* Wt = (float4*)d_ws;   // 2688 float4 = 43 KB scratch

    int B = in_sizes[0] / 210;
    int blocks = (B + GROUPS_PER_BLOCK - 1) / GROUPS_PER_BLOCK;

    transpose_W_kernel<<<11, 256, 0, stream>>>(W, Wt);
    capsnet_kernel<<<blocks, THREADS, 0, stream>>>(x, W_pc, b_pc, Wt, niter, out, B);
}

// Round 5
// 224.805 us; speedup vs baseline: 3.6752x; 3.6752x over previous
//
#include <hip/hip_runtime.h>
#include <math.h>

#define GPB 8        // batch elements (groups) per block; 32 lanes per group
#define THREADS 256

// ---- 16-lane-row sum via DPP row rotates (VALU pipe, no LDS) ----
template<int CTRL>
__device__ __forceinline__ float dpp_add(float x) {
    int xi = __builtin_bit_cast(int, x);
    int yi = __builtin_amdgcn_update_dpp(0, xi, CTRL, 0xF, 0xF, false);
    return x + __builtin_bit_cast(float, yi);
}
__device__ __forceinline__ float row16_sum(float x) {
    x = dpp_add<0x121>(x);  // row_ror:1
    x = dpp_add<0x122>(x);  // row_ror:2
    x = dpp_add<0x124>(x);  // row_ror:4
    x = dpp_add<0x128>(x);  // row_ror:8
    return x;               // every lane in the 16-row holds the row sum
}
// ---- exchange-with-lane^16 and add (pairs the two kh half-rows) ----
__device__ __forceinline__ float xor16_add(float x) {
    int y = __builtin_amdgcn_ds_swizzle(__builtin_bit_cast(int, x), 0x401F);
    return x + __builtin_bit_cast(float, y);
}
__device__ __forceinline__ float rcpf_(float x) { return __builtin_amdgcn_rcpf(x); }

// ---- setup: W[7,12,8,16] -> Wt[((n*8+j)*2+q)*32 + l] float4, l=(kh,t) ----
// lane l: kh=l>>4, m=min(l&15,11); entry covers k = kh*8 + q*4 .. +3
__global__ void transpose_W_kernel(const float* __restrict__ W,
                                   float4* __restrict__ Wt) {
    int i = blockIdx.x * blockDim.x + threadIdx.x;   // 7*8*2*32 = 3584
    if (i < 3584) {
        int l  = i & 31;
        int r  = i >> 5;          // (n*8+j)*2 + q
        int q  = r & 1;
        int j  = (r >> 1) & 7;
        int n  = r >> 4;
        int kh = l >> 4;
        int t  = l & 15;
        int mm = (t < 12) ? t : 11;
        const float* src = W + (((size_t)(n * 12 + mm) * 8 + j) * 16 + kh * 8 + q * 4);
        Wt[i] = *(const float4*)src;
    }
}

// 32 lanes per batch element: lane = (kh = k-half, t = output capsule m).
// Lanes t=12..15 are padding (exp=0 through softmax, never store).
__global__ __launch_bounds__(THREADS) void capsnet_kernel(
    const float* __restrict__ x,      // [B,210]
    const float* __restrict__ W_pc,   // [7,8,30]
    const float* __restrict__ b_pc,   // [7,8]
    const float4* __restrict__ Wt,    // transposed W, see above
    const int*  __restrict__ p_niter,
    float* __restrict__ out,          // [B,12]
    int B)
{
    __shared__ float xs[GPB][210];
    __shared__ float us[GPB][56];

    const int tid = threadIdx.x;
    const int g   = tid >> 5;      // group (batch element) within block
    const int l   = tid & 31;      // lane within group
    const int kh  = l >> 4;        // k-half: owns k = kh*8 .. kh*8+7
    const int t   = l & 15;        // candidate capsule index
    int b = blockIdx.x * GPB + g;
    const bool valid_b = (b < B);
    if (!valid_b) b = B - 1;
    const int niter = *p_niter;

    // ---- stage x[b] into LDS (105 float2 per row, 32 lanes) ----
    {
        const float2* xrow = (const float2*)(x + (size_t)b * 210);
        float2* xdst = (float2*)&xs[g][0];
        #pragma unroll
        for (int i = 0; i < 4; ++i) {
            int idx = l + 32 * i;
            if (idx < 105) xdst[idx] = xrow[idx];
        }
    }
    __syncthreads();

    // ---- primary capsules: pc[n][o] = x[n]·W_pc[n][o] + b_pc[n][o] ----
    #pragma unroll
    for (int i = 0; i < 2; ++i) {
        int idx = l + 32 * i;                 // idx = n*8 + o (56 outputs)
        if (idx < 56) {
            int n = idx >> 3;
            const float2* wrow2 = (const float2*)(W_pc + idx * 30);
            const float2* xr2   = (const float2*)&xs[g][n * 30];
            float acc = b_pc[idx];
            #pragma unroll
            for (int gg = 0; gg < 15; ++gg) {
                float2 wv = wrow2[gg];
                float2 xv = xr2[gg];
                acc += xv.x * wv.x;
                acc += xv.y * wv.y;
            }
            us[g][idx] = acc;
        }
    }
    __syncthreads();

    // ---- squash primary capsules (lanes 0..6, one n each) ----
    if (l < 7) {
        float vals[8];
        float s2 = 0.f;
        #pragma unroll
        for (int o = 0; o < 8; ++o) {
            vals[o] = us[g][l * 8 + o];
            s2 += vals[o] * vals[o];
        }
        float nrm = sqrtf(s2);
        float f = nrm * rcpf_((1.f + s2) * (nrm + 1e-8f));
        #pragma unroll
        for (int o = 0; o < 8; ++o) us[g][l * 8 + o] = vals[o] * f;
    }
    __syncthreads();

    // ---- u_hat[n][m=t][k = kh*8 + kk], kk=0..7, in registers ----
    float uh[7][8];
    #pragma unroll
    for (int n = 0; n < 7; ++n) {
        float uu[8];
        {
            float4 a  = *(const float4*)&us[g][n * 8];
            float4 c4 = *(const float4*)&us[g][n * 8 + 4];
            uu[0] = a.x;  uu[1] = a.y;  uu[2] = a.z;  uu[3] = a.w;
            uu[4] = c4.x; uu[5] = c4.y; uu[6] = c4.z; uu[7] = c4.w;
        }
        #pragma unroll
        for (int kk = 0; kk < 8; ++kk) uh[n][kk] = 0.f;
        #pragma unroll
        for (int j = 0; j < 8; ++j) {
            float uj = uu[j];
            const float4* base = Wt + (size_t)(n * 8 + j) * 64 + l;
            float4 w0 = base[0];    // k = kh*8 + 0..3
            float4 w1 = base[32];   // k = kh*8 + 4..7
            uh[n][0] += uj * w0.x;  uh[n][1] += uj * w0.y;
            uh[n][2] += uj * w0.z;  uh[n][3] += uj * w0.w;
            uh[n][4] += uj * w1.x;  uh[n][5] += uj * w1.y;
            uh[n][6] += uj * w1.z;  uh[n][7] += uj * w1.w;
        }
    }

    // ---- dynamic routing ----
    const bool active = (t < 12);
    float blog[7];
    float vnorm = 0.f;

    // iteration 0: b == 0 => c == 1/12 exactly (softmax of zeros)
    {
        float s[8];
        #pragma unroll
        for (int kk = 0; kk < 8; ++kk) s[kk] = uh[0][kk];
        #pragma unroll
        for (int n = 1; n < 7; ++n)
            #pragma unroll
            for (int kk = 0; kk < 8; ++kk) s[kk] += uh[n][kk];
        const float c0 = 1.0f / 12.0f;
        #pragma unroll
        for (int kk = 0; kk < 8; ++kk) s[kk] *= c0;
        float s2l = 0.f;
        #pragma unroll
        for (int kk = 0; kk < 8; ++kk) s2l += s[kk] * s[kk];
        float s2 = xor16_add(s2l);            // full 16-k norm^2
        float nrm = sqrtf(s2);
        float f = nrm * rcpf_((1.f + s2) * (nrm + 1e-8f));
        if (niter == 1) {
            vnorm = f * nrm;
        } else {
            #pragma unroll
            for (int kk = 0; kk < 8; ++kk) s[kk] *= f;   // s -> v (my k-half)
            #pragma unroll
            for (int n = 0; n < 7; ++n) {
                float dl = 0.f;
                #pragma unroll
                for (int kk = 0; kk < 8; ++kk) dl += uh[n][kk] * s[kk];
                blog[n] = xor16_add(dl);      // full dot over 16 k
            }
        }
    }

    for (int it = 1; it < niter; ++it) {
        // softmax over m within each 16-lane row (no max-sub: logits bounded;
        // inactive lanes contribute exp=0). Both kh rows compute identically.
        float c[7];
        #pragma unroll
        for (int n = 0; n < 7; ++n) {
            float e  = active ? __expf(blog[n]) : 0.f;
            float sm = row16_sum(e);
            c[n] = e * rcpf_(sm);
        }
        float s[8];
        #pragma unroll
        for (int kk = 0; kk < 8; ++kk) s[kk] = 0.f;
        #pragma unroll
        for (int n = 0; n < 7; ++n) {
            float cn = c[n];
            #pragma unroll
            for (int kk = 0; kk < 8; ++kk) s[kk] += cn * uh[n][kk];
        }
        float s2l = 0.f;
        #pragma unroll
        for (int kk = 0; kk < 8; ++kk) s2l += s[kk] * s[kk];
        float s2 = xor16_add(s2l);
        float nrm = sqrtf(s2);
        float f = nrm * rcpf_((1.f + s2) * (nrm + 1e-8f));
        if (it == niter - 1) {
            vnorm = f * nrm;
        } else {
            #pragma unroll
            for (int kk = 0; kk < 8; ++kk) s[kk] *= f;   // s -> v
            #pragma unroll
            for (int n = 0; n < 7; ++n) {
                float dl = 0.f;
                #pragma unroll
                for (int kk = 0; kk < 8; ++kk) dl += uh[n][kk] * s[kk];
                blog[n] += xor16_add(dl);
            }
        }
    }

    if (active && (kh == 0) && valid_b) out[(size_t)b * 12 + t] = vnorm;
}

extern "C" void kernel_launch(void* const* d_in, const int* in_sizes, int n_in,
                              void* d_out, int out_size, void* d_ws, size_t ws_size,
                              hipStream_t stream) {
    const float* x    = (const float*)d_in[0];
    const float* W_pc = (const float*)d_in[1];
    const float* b_pc = (const float*)d_in[2];
    const float* W    = (const float*)d_in[3];
    const int* niter  = (const int*)d_in[4];
    float* out = (float*)d_out;

    float4* Wt = (float4*)d_ws;   // 3584 float4 = 57 KB scratch

    int B = in_sizes[0] / 210;
    int blocks = (B + GPB - 1) / GPB;

    transpose_W_kernel<<<14, 256, 0, stream>>>(W, Wt);
    capsnet_kernel<<<blocks, THREADS, 0, stream>>>(x, W_pc, b_pc, Wt, niter, out, B);
}